// Round 1
// 1106.062 us; speedup vs baseline: 1.1768x; 1.1768x over previous
//
#include <hip/hip_runtime.h>

// RNN scan: h <- tanh(x_t @ W_ih^T + h @ W_hh^T + b), 2048 steps, 1 block/batch.
// v2: 512 threads = 32 row-groups x 16 col-groups (was 256 = 16x16).
// Thread (g,c) owns rows 4g..4g+3, cols 8c..8c+7 of BOTH W matrices (64 VGPRs).
// 2 waves/SIMD (was 1) hides the per-step serial chain (barrier skew, ds_read h
// ~120cy, DPP hazards, exp chain). Reduction: 4 accs -> xor1,xor2 scatter +
// ror4,ror8 all-reduce (6 sel + 5 DPP, was 12 sel + 10 DPP); tanh x1 (was x2).
// xbuf XOR-swizzled (f ^= (f>>3)&1 on float4 index) -> 4-way read conflict
// becomes free 2-way; swizzle is per-thread-constant (zero per-step cost).
// h double-buffered with +4/8-rows padding -> 2-way (free) aliasing.

#define BATCH 256
#define SEQ   2048
#define HID   128
#define CH    16
#define NCHUNK (SEQ / CH)

// DPP ctrl: quad_perm[1,0,3,2]=0xB1 (xor1), quad_perm[2,3,0,1]=0x4E (xor2),
// row_ror:4=0x124, row_ror:8=0x128 (rows of 16 lanes on gfx9+)
template <int CTRL>
__device__ __forceinline__ float dpp_movf(float x) {
    return __int_as_float(__builtin_amdgcn_mov_dpp(__float_as_int(x), CTRL, 0xF, 0xF, true));
}

__device__ __forceinline__ float tanh_fast(float x) {
    x = fminf(fmaxf(x, -12.0f), 12.0f);
    float e = __expf(2.0f * x);
    return 1.0f - __fdividef(2.0f, e + 1.0f);
}

__global__ __launch_bounds__(512, 2) void rnn_scan_kernel(
    const float* __restrict__ x,    // [B, S, 128]
    const float* __restrict__ Wih,  // [128, 128]
    const float* __restrict__ bih,  // [128]
    const float* __restrict__ Whh,  // [128, 128]
    const float* __restrict__ bhh,  // [128]
    float* __restrict__ out)        // [B, 128]
{
    const int b = blockIdx.x;
    const int t = threadIdx.x;
    const int g = t >> 4;          // row group: rows 4g..4g+3
    const int c = t & 15;          // col group: cols 8c..8c+7
    const int colbase = c << 3;
    const int rowbase = g << 2;

    __shared__ __align__(16) float xbuf[2][CH * HID];  // 2 x 8 KB, XOR-swizzled
    __shared__ __align__(16) float hbuf[2][192];       // padded: p(r) = r + 4*(r>>3)

    // --- W tiles into registers: 4 rows x 8 cols x 2 mats = 64 VGPRs ---
    float4 wi[4][2], wh[4][2];
#pragma unroll
    for (int r = 0; r < 4; ++r) {
        const float* pi = Wih + (rowbase + r) * HID + colbase;
        const float* ph = Whh + (rowbase + r) * HID + colbase;
        wi[r][0] = *(const float4*)(pi);
        wi[r][1] = *(const float4*)(pi + 4);
        wh[r][0] = *(const float4*)(ph);
        wh[r][1] = *(const float4*)(ph + 4);
    }

    // reduce-scatter row assignment: lane class m = c&3 ends with row 4g + o(m)
    const int m = c & 3;
    const int o = ((m & 1) << 1) | ((m >> 1) & 1);   // 0,2,1,3 for m=0..3
    const int row0 = rowbase + o;
    const float bias = bih[row0] + bhh[row0];
    const int hw = row0 + ((row0 >> 3) << 2);        // padded index of row0

    // XOR-swizzled xbuf addressing (float4 index f -> f ^ ((f>>3)&1)):
    // read offsets (floats, per-thread constant):
    const int bx = (c >> 2) & 1;
    const int xoff0 = (((c << 1) ^ bx) << 2);        // holds logical cols 8c..8c+3
    const int xoff1 = ((((c << 1) | 1) ^ bx) << 2);  // holds logical cols 8c+4..8c+7
    const int sidx = t ^ ((t >> 3) & 1);             // staging store float4 index

    const float* xsrc = x + (size_t)b * (SEQ * HID);

    // --- prologue: stage chunk 0 (512 x float4 = 8 KB), zero h ---
    {
        const float4* gp = (const float4*)xsrc;
        ((float4*)&xbuf[0][0])[sidx] = gp[t];
    }
    if (t < 192) hbuf[0][t] = 0.0f;
    __syncthreads();

    int cur = 0;
    for (int chn = 0; chn < NCHUNK; ++chn) {
        float4 q0;
        const bool pf = (chn + 1 < NCHUNK);
        if (pf) {
            const float4* gp = (const float4*)(xsrc + (size_t)(chn + 1) * (CH * HID));
            q0 = gp[t];
        }
        const float* xb = &xbuf[chn & 1][0];
#pragma unroll 1
        for (int s = 0; s < CH; ++s) {
            const float* xr = xb + s * HID;
            const float* hr = &hbuf[cur][12 * c];    // p(8c) = 12c, 16B-aligned
            float4 hv0 = *(const float4*)(hr);
            float4 hv1 = *(const float4*)(hr + 4);
            float4 xv0 = *(const float4*)(xr + xoff0);
            float4 xv1 = *(const float4*)(xr + xoff1);

            float a[4];
#pragma unroll
            for (int r = 0; r < 4; ++r) {
                float acc;
                acc = wi[r][0].x * xv0.x;
                acc = fmaf(wi[r][0].y, xv0.y, acc);
                acc = fmaf(wi[r][0].z, xv0.z, acc);
                acc = fmaf(wi[r][0].w, xv0.w, acc);
                acc = fmaf(wi[r][1].x, xv1.x, acc);
                acc = fmaf(wi[r][1].y, xv1.y, acc);
                acc = fmaf(wi[r][1].z, xv1.z, acc);
                acc = fmaf(wi[r][1].w, xv1.w, acc);
                acc = fmaf(wh[r][0].x, hv0.x, acc);
                acc = fmaf(wh[r][0].y, hv0.y, acc);
                acc = fmaf(wh[r][0].z, hv0.z, acc);
                acc = fmaf(wh[r][0].w, hv0.w, acc);
                acc = fmaf(wh[r][1].x, hv1.x, acc);
                acc = fmaf(wh[r][1].y, hv1.y, acc);
                acc = fmaf(wh[r][1].z, hv1.z, acc);
                acc = fmaf(wh[r][1].w, hv1.w, acc);
                a[r] = acc;
            }

            // --- DPP reduce-scatter over the 16-lane col dimension ---
            const bool b0 = (c & 1) != 0;
            const bool b1 = (c & 2) != 0;
            // round 1: xor 1 (quad_perm): even lanes keep rows {0,1}, odd {2,3}
            float k0 = b0 ? a[2] : a[0], s0 = b0 ? a[0] : a[2];
            float k1 = b0 ? a[3] : a[1], s1 = b0 ? a[1] : a[3];
            float t0 = k0 + dpp_movf<0xB1>(s0);
            float t1 = k1 + dpp_movf<0xB1>(s1);
            // round 2: xor 2 (quad_perm): 2 -> 1, row = 4g + o(c&3)
            float k2 = b1 ? t1 : t0, s2 = b1 ? t0 : t1;
            float u = k2 + dpp_movf<0x4E>(s2);
            // rounds 3,4: all-reduce over lanes {c, c+4, c+8, c+12} via row_ror
            u += dpp_movf<0x124>(u);
            u += dpp_movf<0x128>(u);

            float h = tanh_fast(u + bias);
            if (c < 4) {  // lanes c>=4 hold duplicates
                hbuf[cur ^ 1][hw] = h;
            }

            if (s == CH - 1 && pf) {
                ((float4*)&xbuf[(chn + 1) & 1][0])[sidx] = q0;
            }
            __syncthreads();
            cur ^= 1;
        }
    }
    // cur == 0 after 2048 toggles; hbuf[0] holds h_final (padded layout)
    if (t < HID) out[(size_t)b * HID + t] = hbuf[cur][t + ((t >> 3) << 2)];
}

extern "C" void kernel_launch(void* const* d_in, const int* in_sizes, int n_in,
                              void* d_out, int out_size, void* d_ws, size_t ws_size,
                              hipStream_t stream) {
    const float* x   = (const float*)d_in[0];
    const float* Wih = (const float*)d_in[1];
    const float* bih = (const float*)d_in[2];
    const float* Whh = (const float*)d_in[3];
    const float* bhh = (const float*)d_in[4];
    float* out = (float*)d_out;

    rnn_scan_kernel<<<BATCH, 512, 0, stream>>>(x, Wih, bih, Whh, bhh, out);
}

// Round 4
// 1082.079 us; speedup vs baseline: 1.2029x; 1.0222x over previous
//
#include <hip/hip_runtime.h>

// RNN scan: h <- tanh(x_t @ W_ih^T + h @ W_hh^T + b), 2048 steps, 1 block/batch.
// v3.2: identical to v3.1 (x-projection on the idle MFMA pipe, one chunk
// ahead; serial step = 32 fmac h@Whh + DPP reduce + tanh) plus hardening:
// xbf is now __align__(16) — it is accessed as uint2/bf16x8 (ds_write_b64 /
// ds_read_b128) and a ushort array carries no natural 16B alignment.
// Per 16-step chunk: xw = X_chunk[16x128] @ Wih^T via mfma_f32_16x16x32_bf16
// in fp32-accurate bf16 hi/lo 3-pass form (hi*hi + hi*lo + lo*hi; ~1e-5 err),
// 12 MFMA/wave/chunk, double-buffered, computed at s==0 off the critical path.
// LDS XOR-swizzle applied to the FULL byte offset (incl. kk*64) on reads.
// 512 threads = 32 rowgroups x 16 colgroups; thread owns 4 rows x 8 cols of Whh.

#define BATCH 256
#define SEQ   2048
#define HID   128
#define CH    16
#define NCHUNK (SEQ / CH)

typedef __attribute__((ext_vector_type(8))) short bf16x8;
typedef __attribute__((ext_vector_type(4))) float f32x4;

// DPP ctrl: quad_perm[1,0,3,2]=0xB1 (xor1), quad_perm[2,3,0,1]=0x4E (xor2),
// row_ror:4=0x124, row_ror:8=0x128 (rows of 16 lanes on gfx9+)
template <int CTRL>
__device__ __forceinline__ float dpp_movf(float x) {
    return __int_as_float(__builtin_amdgcn_mov_dpp(__float_as_int(x), CTRL, 0xF, 0xF, true));
}

__device__ __forceinline__ float tanh_fast(float x) {
    x = fminf(fmaxf(x, -12.0f), 12.0f);
    float e = __expf(2.0f * x);
    return 1.0f - __fdividef(2.0f, e + 1.0f);
}

// split float -> (hi, lo) bf16 pair capturing ~16 mantissa bits
__device__ __forceinline__ void bf16_split(float v, short& hi, short& lo) {
    unsigned u = __float_as_uint(v);
    unsigned hb = (u + 0x8000u) & 0xFFFF0000u;   // round-to-nearest-ish hi
    float hf = __uint_as_float(hb);
    float r = v - hf;
    unsigned ru = __float_as_uint(r);
    hi = (short)(hb >> 16);
    lo = (short)((ru + 0x8000u) >> 16);
}

__global__ __launch_bounds__(512, 2) void rnn_scan_kernel(
    const float* __restrict__ x,    // [B, S, 128]
    const float* __restrict__ Wih,  // [128, 128]
    const float* __restrict__ bih,  // [128]
    const float* __restrict__ Whh,  // [128, 128]
    const float* __restrict__ bhh,  // [128]
    float* __restrict__ out)        // [B, 128]
{
    const int b = blockIdx.x;
    const int t = threadIdx.x;
    const int g = t >> 4;          // row group: rows 4g..4g+3
    const int c = t & 15;          // col group: cols 8c..8c+7 (of h)
    const int colbase = c << 3;
    const int rowbase = g << 2;
    const int lane = t & 63;
    const int w = t >> 6;          // wave 0..7

    __shared__ __align__(16) ushort xbf[2][2][CH * HID];  // [buf][hi/lo] bf16 x, swizzled (16 KB)
    __shared__ __align__(16) float  xwbuf[2][CH * HID];   // precomputed xw (16 KB)
    __shared__ __align__(16) float  hbuf[2][192];         // padded: p(r) = r + 4*(r>>3)

    // --- Whh tile into registers: 4 rows x 8 cols = 32 VGPRs ---
    float4 wh[4][2];
#pragma unroll
    for (int r = 0; r < 4; ++r) {
        const float* ph = Whh + (rowbase + r) * HID + colbase;
        wh[r][0] = *(const float4*)(ph);
        wh[r][1] = *(const float4*)(ph + 4);
    }

    // --- Wih B-fragments (bf16 hi/lo), canonical 16x16x32 B layout:
    // lane holds B[k=(lane>>4)*8+j][col=lane&15], tile col offset 16w.
    // B[k][col] = Wih[col_global][k] -> 8 k-contiguous floats per frag. ---
    const int bcol = (w << 4) + (lane & 15);   // global output col (h row)
    const int krow = (lane >> 4) << 3;         // k base within 32-block
    bf16x8 bhi[4], blo[4];
#pragma unroll
    for (int kk = 0; kk < 4; ++kk) {
        const float* src = Wih + bcol * HID + kk * 32 + krow;
        float4 u0 = *(const float4*)(src);
        float4 u1 = *(const float4*)(src + 4);
        short hh, ll;
        bf16_split(u0.x, hh, ll); bhi[kk][0] = hh; blo[kk][0] = ll;
        bf16_split(u0.y, hh, ll); bhi[kk][1] = hh; blo[kk][1] = ll;
        bf16_split(u0.z, hh, ll); bhi[kk][2] = hh; blo[kk][2] = ll;
        bf16_split(u0.w, hh, ll); bhi[kk][3] = hh; blo[kk][3] = ll;
        bf16_split(u1.x, hh, ll); bhi[kk][4] = hh; blo[kk][4] = ll;
        bf16_split(u1.y, hh, ll); bhi[kk][5] = hh; blo[kk][5] = ll;
        bf16_split(u1.z, hh, ll); bhi[kk][6] = hh; blo[kk][6] = ll;
        bf16_split(u1.w, hh, ll); bhi[kk][7] = hh; blo[kk][7] = ll;
    }

    // reduce-scatter row assignment: lane class m = c&3 ends with row 4g + o(m)
    const int m = c & 3;
    const int o = ((m & 1) << 1) | ((m >> 1) & 1);   // 0,2,1,3 for m=0..3
    const int row0 = rowbase + o;
    const float bias = bih[row0] + bhh[row0];
    const int hw = row0 + ((row0 >> 3) << 2);        // padded index of row0

    const float* xsrc = x + (size_t)b * (SEQ * HID);

    // stage one chunk of x as bf16 hi/lo into xbf[buf] (swizzled rows)
    auto stage_bf16 = [&](float4 q, int buf) {
        const int srow = t >> 5;                       // step row 0..15
        const int sw = ((srow << 8) + ((t & 31) << 3)) ^ ((srow & 7) << 4);
        short h0, l0, h1, l1, h2, l2, h3, l3;
        bf16_split(q.x, h0, l0); bf16_split(q.y, h1, l1);
        bf16_split(q.z, h2, l2); bf16_split(q.w, h3, l3);
        uint2 ph, pl;
        ph.x = (unsigned)(ushort)h0 | ((unsigned)(ushort)h1 << 16);
        ph.y = (unsigned)(ushort)h2 | ((unsigned)(ushort)h3 << 16);
        pl.x = (unsigned)(ushort)l0 | ((unsigned)(ushort)l1 << 16);
        pl.y = (unsigned)(ushort)l2 | ((unsigned)(ushort)l3 << 16);
        *(uint2*)((char*)&xbf[buf][0][0] + sw) = ph;
        *(uint2*)((char*)&xbf[buf][1][0] + sw) = pl;
    };

    // xw(m) = X_chunk(m) @ Wih^T via 12 MFMA (hi*hi + hi*lo + lo*hi)
    auto compute_xw = [&](int mm) {
        const int buf = mm & 1;
        const int arow = lane & 15;
        const int rowb = (arow << 8) + ((lane >> 4) << 4);   // unswizzled base
        const int swz = (arow & 7) << 4;                     // XOR bits 4-6
        const char* hp = (const char*)&xbf[buf][0][0];
        const char* lp = (const char*)&xbf[buf][1][0];
        f32x4 acc0 = {0.0f, 0.0f, 0.0f, 0.0f};
        f32x4 acc1 = {0.0f, 0.0f, 0.0f, 0.0f};
#pragma unroll
        for (int kk = 0; kk < 4; ++kk) {
            const int off = (rowb + kk * 64) ^ swz;          // XOR after full sum
            bf16x8 ah = *(const bf16x8*)(hp + off);
            bf16x8 al = *(const bf16x8*)(lp + off);
            f32x4& acc = (kk & 1) ? acc1 : acc0;             // 2 independent chains
            acc = __builtin_amdgcn_mfma_f32_16x16x32_bf16(ah, bhi[kk], acc, 0, 0, 0);
            acc = __builtin_amdgcn_mfma_f32_16x16x32_bf16(ah, blo[kk], acc, 0, 0, 0);
            acc = __builtin_amdgcn_mfma_f32_16x16x32_bf16(al, bhi[kk], acc, 0, 0, 0);
        }
        // C/D layout (verified m89): col = lane&15, row = (lane>>4)*4 + r
        float* xw = &xwbuf[buf][0];
        const int crow = (lane >> 4) << 2;
#pragma unroll
        for (int r = 0; r < 4; ++r) xw[(crow + r) * HID + bcol] = acc0[r] + acc1[r];
    };

    // --- prologue: stage chunks 0,1 (bf16), zero h, xw(0) ---
    {
        const float4* gp = (const float4*)xsrc;
        float4 a0 = gp[t];
        float4 a1 = gp[512 + t];
        stage_bf16(a0, 0);
        stage_bf16(a1, 1);
    }
    if (t < 192) hbuf[0][t] = 0.0f;
    __syncthreads();
    compute_xw(0);
    __syncthreads();

    int cur = 0;
    for (int n = 0; n < NCHUNK; ++n) {
        float4 q0;
        const bool pf = (n + 2 < NCHUNK);
        if (pf) {
            const float4* gp = (const float4*)(xsrc + (size_t)(n + 2) * (CH * HID));
            q0 = gp[t];
        }
        const float* xwc = &xwbuf[n & 1][0];
#pragma unroll 1
        for (int s = 0; s < CH; ++s) {
            float xwv = 0.0f;
            if (c < 4) xwv = xwc[s * HID + row0];    // 16 lanes, distinct banks
            const float* hr = &hbuf[cur][12 * c];    // p(8c) = 12c, 16B-aligned
            float4 hv0 = *(const float4*)(hr);
            float4 hv1 = *(const float4*)(hr + 4);

            float a[4];
#pragma unroll
            for (int r = 0; r < 4; ++r) {
                float acc;
                acc = wh[r][0].x * hv0.x;
                acc = fmaf(wh[r][0].y, hv0.y, acc);
                acc = fmaf(wh[r][0].z, hv0.z, acc);
                acc = fmaf(wh[r][0].w, hv0.w, acc);
                acc = fmaf(wh[r][1].x, hv1.x, acc);
                acc = fmaf(wh[r][1].y, hv1.y, acc);
                acc = fmaf(wh[r][1].z, hv1.z, acc);
                acc = fmaf(wh[r][1].w, hv1.w, acc);
                a[r] = acc;
            }

            // --- DPP reduce-scatter over the 16-lane col dimension ---
            const bool b0 = (c & 1) != 0;
            const bool b1 = (c & 2) != 0;
            float k0 = b0 ? a[2] : a[0], s0 = b0 ? a[0] : a[2];
            float k1 = b0 ? a[3] : a[1], s1 = b0 ? a[1] : a[3];
            float t0 = k0 + dpp_movf<0xB1>(s0);
            float t1 = k1 + dpp_movf<0xB1>(s1);
            float k2 = b1 ? t1 : t0, s2 = b1 ? t0 : t1;
            float u = k2 + dpp_movf<0x4E>(s2);
            u += dpp_movf<0x124>(u);
            u += dpp_movf<0x128>(u);

            float hval = tanh_fast(u + bias + xwv);
            if (c < 4) {  // lanes c>=4 hold duplicates
                hbuf[cur ^ 1][hw] = hval;
            }

            // off-critical-path work, overlapped with other waves' VALU:
            if (s == 0 && n + 1 < NCHUNK) compute_xw(n + 1);
            if (s == CH - 1 && pf) stage_bf16(q0, n & 1);  // x(n+2) -> xbf[(n+2)&1]

            __syncthreads();
            cur ^= 1;
        }
    }
    // cur == 0 after 2048 toggles; hbuf[0] holds h_final (padded layout)
    if (t < HID) out[(size_t)b * HID + t] = hbuf[cur][t + ((t >> 3) << 2)];
}

extern "C" void kernel_launch(void* const* d_in, const int* in_sizes, int n_in,
                              void* d_out, int out_size, void* d_ws, size_t ws_size,
                              hipStream_t stream) {
    const float* x   = (const float*)d_in[0];
    const float* Wih = (const float*)d_in[1];
    const float* bih = (const float*)d_in[2];
    const float* Whh = (const float*)d_in[3];
    const float* bhh = (const float*)d_in[4];
    float* out = (float*)d_out;

    rnn_scan_kernel<<<BATCH, 512, 0, stream>>>(x, Wih, bih, Whh, bhh, out);
}